// Round 4
// baseline (2896.873 us; speedup 1.0000x reference)
//
#include <hip/hip_runtime.h>
#include <math.h>

#define NN   20000
#define EE   80000
#define ELP  100000   // EE + NN self loops
#define NGR  64
#define EMB  780
#define W3   2340
#define EMBP 800      // 780 padded to mult of 32
#define W3P  2368     // 2340 padded to mult of 32

static inline int cdiv_i(long long a, long long b){ return (int)((a + b - 1) / b); }

typedef _Float16 f16;
typedef _Float16 f16x2 __attribute__((ext_vector_type(2)));
typedef _Float16 f16x4 __attribute__((ext_vector_type(4)));
typedef _Float16 f16x8 __attribute__((ext_vector_type(8)));
typedef float    f32x4 __attribute__((ext_vector_type(4)));

__device__ __forceinline__ void async_ld16(const f16* g, f16* l){
    __builtin_amdgcn_global_load_lds(
        (const __attribute__((address_space(1))) unsigned int*)g,
        (__attribute__((address_space(3))) unsigned int*)l,
        16, 0, 0);
}

// ---------------- utility kernels ----------------
__global__ void k_zero_f32(float* p, int n){
    int i = blockIdx.x*256 + threadIdx.x; if (i < n) p[i] = 0.f;
}
__global__ void k_zero_i32(int* p, int n){
    int i = blockIdx.x*256 + threadIdx.x; if (i < n) p[i] = 0;
}
__global__ void k_copy_i32(const int* __restrict__ s, int* __restrict__ d, int n){
    int i = blockIdx.x*256 + threadIdx.x; if (i < n) d[i] = s[i];
}

// W [K,N] fp32 -> Wt [N,KP] f16, optional per-k scale (BN fold), pad k zeroed
__global__ void k_transpose(const float* __restrict__ W, f16* __restrict__ Wt,
                            const float* __restrict__ sc, int K, int N, int KP){
    __shared__ float T[32][33];
    int n0 = blockIdx.x*32, k0 = blockIdx.y*32;
    int tx = threadIdx.x, ty = threadIdx.y;   // 32 x 8
#pragma unroll
    for (int r = 0; r < 4; r++){
        int k = k0 + ty + r*8;
        float v = 0.f;
        if (k < K && n0 + tx < N){
            v = W[(size_t)k*N + n0 + tx];
            if (sc) v *= sc[k];
        }
        T[ty + r*8][tx] = v;
    }
    __syncthreads();
#pragma unroll
    for (int r = 0; r < 4; r++){
        int n = n0 + ty + r*8;
        int k = k0 + tx;
        if (n < N && k < KP) Wt[(size_t)n*KP + k] = (f16)T[tx][ty + r*8];
    }
}

// dvec[n] = sum_k sh[k] * W[k,n]  (rank-1 BN-shift correction)
__global__ void k_dvec(const float* __restrict__ W, const float* __restrict__ sh,
                       float* __restrict__ dvec, int K, int N){
    int n = blockIdx.x*256 + threadIdx.x; if (n >= N) return;
    float s = 0.f;
    for (int k = 0; k < K; k++) s += sh[k] * W[(size_t)k*N + n];
    dvec[n] = s;
}

// ---------------- h0 ----------------
__global__ void k_build_h(const float* __restrict__ x, const float* __restrict__ tW,
                          const float* __restrict__ tb, f16* __restrict__ h){
    int idx = blockIdx.x*256 + threadIdx.x;
    if (idx >= NN*EMBP) return;
    int n = idx / EMBP, c = idx - n*EMBP;
    const float* xr = x + (size_t)n*772;
    float v;
    if (c < 768) v = xr[c];
    else if (c < EMB){
        int j = c - 768;
        v = tb[j] + xr[768]*tW[j] + xr[769]*tW[12+j] + xr[770]*tW[24+j] + xr[771]*tW[36+j];
    } else v = 0.f;
    h[idx] = (f16)v;
}

// ---------------- CSR build ----------------
__global__ void k_deg(const int* __restrict__ ei, int* __restrict__ deg){
    int k = blockIdx.x*256 + threadIdx.x; if (k >= ELP) return;
    int d = (k < EE) ? ei[EE + k] : (k - EE);
    atomicAdd(&deg[d], 1);
}

__global__ __launch_bounds__(1024) void k_scan(const int* __restrict__ deg, int* __restrict__ rp){
    __shared__ int buf[1024];
    __shared__ int carry;
    int tid = threadIdx.x;
    if (tid == 0){ carry = 0; rp[0] = 0; }
    __syncthreads();
    for (int base = 0; base < NN; base += 1024){
        int i = base + tid;
        int v = (i < NN) ? deg[i] : 0;
        buf[tid] = v; __syncthreads();
        for (int off = 1; off < 1024; off <<= 1){
            int t = (tid >= off) ? buf[tid-off] : 0;
            __syncthreads();
            buf[tid] += t;
            __syncthreads();
        }
        int incl = buf[tid];
        int tot  = buf[1023];
        if (i < NN) rp[i+1] = carry + incl;
        __syncthreads();
        if (tid == 0) carry += tot;
        __syncthreads();
    }
}

__global__ void k_fill(const int* __restrict__ ei, int* __restrict__ cursor, int* __restrict__ csrc){
    int k = blockIdx.x*256 + threadIdx.x; if (k >= ELP) return;
    int s, d;
    if (k < EE){ s = ei[k]; d = ei[EE + k]; } else { s = k - EE; d = s; }
    int pos = atomicAdd(&cursor[d], 1);
    csrc[pos] = s;
}

// graph ranges from sorted batch: grp[g] = first idx with batch[idx] >= g
__global__ void k_grp(const int* __restrict__ batch, int* __restrict__ grp){
    int g = blockIdx.x*256 + threadIdx.x; if (g > NGR) return;
    int lo = 0, hi = NN;
    while (lo < hi){ int mid = (lo+hi)>>1; if (batch[mid] < g) lo = mid+1; else hi = mid; }
    grp[g] = lo;
}

// ---------------- MFMA f16 GEMM, XCD-pinned strips: C = A[M,KP] @ Bt[N,KP]^T + dvec ----------
__global__ __launch_bounds__(256) void k_gemm_mfma(const f16* __restrict__ A,
                                                   const f16* __restrict__ Bt,
                                                   const float* __restrict__ dvec,
                                                   f16* __restrict__ C,
                                                   int M, int N, int KP, int SN,
                                                   int Mtiles, int NT){
    // decode: all NT n-tiles of one m-strip run on the same XCD (bid%8)
    int bid = blockIdx.x;
    int xcd = bid & 7;
    int j   = bid >> 3;
    int sl  = j / NT;
    int nt  = j - sl*NT;
    int mt  = sl*8 + xcd;
    if (mt >= Mtiles) return;
    int m0 = mt*128, n0 = nt*128;

    __shared__ f16 As[128*32];
    __shared__ f16 Bs[128*32];
    int tid = threadIdx.x;
    int w = tid >> 6, lane = tid & 63;

    int lrow = lane >> 2;
    int lko  = (lane & 3) * 8;

    int i2a = w*2, i2b = w*2 + 1;
    const f16* gA0 = A  + (size_t)min(m0 + i2a*16 + lrow, M-1)*KP + lko;
    const f16* gA1 = A  + (size_t)min(m0 + i2b*16 + lrow, M-1)*KP + lko;
    const f16* gB0 = Bt + (size_t)min(n0 + i2a*16 + lrow, N-1)*KP + lko;
    const f16* gB1 = Bt + (size_t)min(n0 + i2b*16 + lrow, N-1)*KP + lko;
    f16* lA0 = &As[i2a*512]; f16* lA1 = &As[i2b*512];
    f16* lB0 = &Bs[i2a*512]; f16* lB1 = &Bs[i2b*512];

    f32x4 acc[4][4];
#pragma unroll
    for (int i = 0; i < 4; i++)
#pragma unroll
        for (int j2 = 0; j2 < 4; j2++) acc[i][j2] = (f32x4)0.f;

    int wm = (w & 1) * 64, wn = (w >> 1) * 64;
    int lq = lane >> 4, lm = lane & 15;

    for (int kk = 0; kk < KP; kk += 32){
        __syncthreads();
        async_ld16(gA0 + kk, lA0);
        async_ld16(gA1 + kk, lA1);
        async_ld16(gB0 + kk, lB0);
        async_ld16(gB1 + kk, lB1);
        __syncthreads();

        f16x8 aF[4], bF[4];
#pragma unroll
        for (int mi = 0; mi < 4; mi++)
            aF[mi] = *(const f16x8*)&As[(wm + mi*16 + lm)*32 + lq*8];
#pragma unroll
        for (int ni = 0; ni < 4; ni++)
            bF[ni] = *(const f16x8*)&Bs[(wn + ni*16 + lm)*32 + lq*8];
#pragma unroll
        for (int mi = 0; mi < 4; mi++)
#pragma unroll
            for (int ni = 0; ni < 4; ni++)
                acc[mi][ni] = __builtin_amdgcn_mfma_f32_16x16x32_f16(aF[mi], bF[ni], acc[mi][ni], 0, 0, 0);
    }

#pragma unroll
    for (int mi = 0; mi < 4; mi++){
#pragma unroll
        for (int ni = 0; ni < 4; ni++){
            int col = n0 + wn + ni*16 + lm;
            if (col < SN){
                float dv = (col < N) ? dvec[col] : 0.f;
                int rbase = m0 + wm + mi*16 + lq*4;
#pragma unroll
                for (int r = 0; r < 4; r++){
                    int row = rbase + r;
                    if (row < M){
                        float v = (col < N) ? (acc[mi][ni][r] + dv) : 0.f;
                        C[(size_t)row*SN + col] = (f16)v;
                    }
                }
            }
        }
    }
}

// ---------------- attention coefficients ----------------
__global__ void k_att(const f16* __restrict__ hp, const float* __restrict__ asrc,
                      const float* __restrict__ adst, float* __restrict__ a_s,
                      float* __restrict__ a_d, int H, int SP){
    int n = blockIdx.x;
    int wv = threadIdx.x >> 6, lane = threadIdx.x & 63;
    const f16* row = hp + (size_t)n*SP + wv*EMB;
    const float* pa = asrc + wv*EMB;
    const float* pd = adst + wv*EMB;
    float s = 0.f, d = 0.f;
    for (int c = lane; c < EMB; c += 64){ float v = (float)row[c]; s += v*pa[c]; d += v*pd[c]; }
#pragma unroll
    for (int off = 32; off; off >>= 1){ s += __shfl_xor(s, off); d += __shfl_xor(d, off); }
    if (lane == 0){ a_s[n*H + wv] = s; a_d[n*H + wv] = d; }
}

// ---------------- per-dst softmax + aggregation + bias + tanh (f16x4 cols) ----------------
__global__ __launch_bounds__(256) void k_agg(const f16* __restrict__ hp, const int* __restrict__ rp,
                                             const int* __restrict__ csrc, const float* __restrict__ a_s,
                                             const float* __restrict__ a_d, const float* __restrict__ bias,
                                             f16* __restrict__ y, int H, int SP, int W){
    int n = blockIdx.x, tid = threadIdx.x;
    int beg = rp[n], deg = rp[n+1] - beg;

    __shared__ float sm[3], sden[3];
    __shared__ float sal[64*3];
    __shared__ int   ssrc[64];

    if (tid < 64){
        float adn[3];
#pragma unroll
        for (int h = 0; h < 3; h++) adn[h] = (h < H) ? a_d[n*H + h] : 0.f;
        float mx[3] = {-1e30f, -1e30f, -1e30f};
        for (int e = tid; e < deg; e += 64){
            int s = csrc[beg + e];
#pragma unroll
            for (int h = 0; h < 3; h++) if (h < H){
                float v = a_s[s*H + h] + adn[h];
                v = v > 0.f ? v : 0.2f*v;
                mx[h] = fmaxf(mx[h], v);
            }
        }
#pragma unroll
        for (int off = 32; off; off >>= 1){
#pragma unroll
            for (int h = 0; h < 3; h++) mx[h] = fmaxf(mx[h], __shfl_xor(mx[h], off));
        }
        float dn[3] = {0.f, 0.f, 0.f};
        for (int e = tid; e < deg; e += 64){
            int s = csrc[beg + e];
#pragma unroll
            for (int h = 0; h < 3; h++) if (h < H){
                float v = a_s[s*H + h] + adn[h];
                v = v > 0.f ? v : 0.2f*v;
                dn[h] += expf(v - mx[h]);
            }
        }
#pragma unroll
        for (int off = 32; off; off >>= 1){
#pragma unroll
            for (int h = 0; h < 3; h++) dn[h] += __shfl_xor(dn[h], off);
        }
        if (tid == 0){
#pragma unroll
            for (int h = 0; h < 3; h++){ sm[h] = mx[h]; sden[h] = dn[h]; }
        }
    }
    __syncthreads();

    float4 acc4[3];
    int c4[3], hh4[3];
#pragma unroll
    for (int i = 0; i < 3; i++){
        acc4[i] = make_float4(0.f,0.f,0.f,0.f);
        c4[i] = tid*4 + i*1024;
        hh4[i] = (c4[i] < W) ? (c4[i] / EMB) : 0;   // 780 % 4 == 0: quads never straddle heads
    }

    for (int base = 0; base < deg; base += 64){
        int cnt = min(64, deg - base);
        if (tid < cnt) ssrc[tid] = csrc[beg + base + tid];
        if (tid < cnt*H){
            int e = tid / H, h = tid - e*H;
            int s = csrc[beg + base + e];
            float v = a_s[s*H + h] + a_d[n*H + h];
            v = v > 0.f ? v : 0.2f*v;
            sal[e*3 + h] = expf(v - sm[h]) / (sden[h] + 1e-16f);
        }
        __syncthreads();
        for (int e = 0; e < cnt; e++){
            const f16* rowp = hp + (size_t)ssrc[e]*SP;
#pragma unroll
            for (int i = 0; i < 3; i++)
                if (c4[i] < W){
                    f16x4 v = *(const f16x4*)(rowp + c4[i]);
                    float al = sal[e*3 + hh4[i]];
                    acc4[i].x += al * (float)v[0];
                    acc4[i].y += al * (float)v[1];
                    acc4[i].z += al * (float)v[2];
                    acc4[i].w += al * (float)v[3];
                }
        }
        __syncthreads();
    }

#pragma unroll
    for (int i = 0; i < 3; i++){
        int c = c4[i];
        if (c < SP){
            f16x4 o;
            if (c < W){
                o[0] = (f16)tanhf(acc4[i].x + bias[c]);
                o[1] = (f16)tanhf(acc4[i].y + bias[c+1]);
                o[2] = (f16)tanhf(acc4[i].z + bias[c+2]);
                o[3] = (f16)tanhf(acc4[i].w + bias[c+3]);
            } else { o[0]=(f16)0.f; o[1]=(f16)0.f; o[2]=(f16)0.f; o[3]=(f16)0.f; }
            *(f16x4*)(y + (size_t)n*SP + c) = o;
        }
    }
}

// ---------------- BatchNorm stats (f16x4 loads) ----------------
__global__ void k_bnstat(const f16* __restrict__ y, float* __restrict__ psum,
                         float* __restrict__ psq, int W, int SP){
    int c0 = (blockIdx.x*256 + threadIdx.x)*4;
    if (c0 >= W) return;
    int slice = blockIdx.y;   // 0..63
    float s[4] = {0,0,0,0}, s2[4] = {0,0,0,0};
    for (int r = slice; r < NN; r += 64){
        f16x4 u = *(const f16x4*)(y + (size_t)r*SP + c0);
#pragma unroll
        for (int j = 0; j < 4; j++){ float v = (float)u[j]; s[j] += v; s2[j] += v*v; }
    }
#pragma unroll
    for (int j = 0; j < 4; j++){
        atomicAdd(&psum[c0+j], s[j]);
        atomicAdd(&psq[c0+j], s2[j]);
    }
}

// mu/istd + BN fold coefficients: sc = istd*gamma, sh = beta - mu*istd*gamma
__global__ void k_bnfin(const float* __restrict__ psum, const float* __restrict__ psq,
                        const float* __restrict__ gamma, const float* __restrict__ beta,
                        float* __restrict__ mu, float* __restrict__ istd,
                        float* __restrict__ sc, float* __restrict__ sh, int W){
    int c = blockIdx.x*256 + threadIdx.x; if (c >= W) return;
    float m = psum[c] * (1.f/NN);
    float v = psq[c] * (1.f/NN) - m*m;
    float is = 1.f / sqrtf(v + 1e-5f);
    mu[c] = m; istd[c] = is;
    float g = gamma[c];
    sc[c] = is * g;
    sh[c] = beta[c] - m * is * g;
}

// explicit BN apply (final layer only)
__global__ void k_bnapply(f16* __restrict__ y, const float* __restrict__ sc,
                          const float* __restrict__ sh, int W, int SP){
    int idx = blockIdx.x*256 + threadIdx.x;
    int w4 = W >> 2;
    if (idx >= NN * w4) return;
    int row = idx / w4;
    int c = (idx - row*w4) * 4;
    f16* p = y + (size_t)row*SP + c;
    f16x4 u = *(f16x4*)p;
#pragma unroll
    for (int j = 0; j < 4; j++)
        u[j] = (f16)((float)u[j] * sc[c+j] + sh[c+j]);
    *(f16x4*)p = u;
}

// ---------------- segmented pooling (batch sorted) + MLP ----------------
__global__ void k_pool(const f16* __restrict__ h, const int* __restrict__ grp,
                       float* __restrict__ pooled){
    int g = blockIdx.x;
    int c = blockIdx.y*256 + threadIdx.x;
    if (c >= EMB) return;
    int r0 = grp[g], r1 = grp[g+1];
    float s = 0.f;
    for (int r = r0; r < r1; r++) s += (float)h[(size_t)r*EMBP + c];
    pooled[g*EMB + c] = s;
}

__global__ __launch_bounds__(256) void k_mlp(const float* __restrict__ pooled, const int* __restrict__ grp,
                                             const float* __restrict__ W1, const float* __restrict__ b1,
                                             const float* __restrict__ W2, const float* __restrict__ b2,
                                             float* __restrict__ out){
    __shared__ float p[EMB];
    __shared__ float hid[128];
    int g = blockIdx.x, tid = threadIdx.x;
    int cnt = grp[g+1] - grp[g];
    float ic = 1.f / fmaxf((float)cnt, 1.f);
    for (int c = tid; c < EMB; c += 256){
        float v = pooled[g*EMB + c] * ic;
        p[c] = v > 0.f ? v : 0.f;
    }
    __syncthreads();
    if (tid < 128){
        float s = b1[tid];
        for (int k = 0; k < EMB; k++) s += p[k] * W1[k*128 + tid];
        hid[tid] = tanhf(s);
    }
    __syncthreads();
    if (tid < 64){
        float s = b2[tid];
        for (int k = 0; k < 128; k++) s += hid[k] * W2[k*64 + tid];
        out[g*64 + tid] = s;
    }
}

// ---------------- launch ----------------
extern "C" void kernel_launch(void* const* d_in, const int* in_sizes, int n_in,
                              void* d_out, int out_size, void* d_ws, size_t ws_size,
                              hipStream_t stream) {
    (void)in_sizes; (void)n_in; (void)out_size;
    const float* x    = (const float*)d_in[0];
    const int*   ei   = (const int*)  d_in[1];
    const int*   batch= (const int*)  d_in[2];
    const float* tW   = (const float*)d_in[3];
    const float* tb   = (const float*)d_in[4];
    const float* W0   = (const float*)d_in[5];
    const float* as0  = (const float*)d_in[6];
    const float* ad0  = (const float*)d_in[7];
    const float* b0   = (const float*)d_in[8];
    const float* g0   = (const float*)d_in[9];
    const float* be0  = (const float*)d_in[10];
    const float* W1   = (const float*)d_in[11];
    const float* as1  = (const float*)d_in[12];
    const float* ad1  = (const float*)d_in[13];
    const float* b1   = (const float*)d_in[14];
    const float* g1   = (const float*)d_in[15];
    const float* be1  = (const float*)d_in[16];
    const float* W2   = (const float*)d_in[17];
    const float* as2  = (const float*)d_in[18];
    const float* ad2  = (const float*)d_in[19];
    const float* b2   = (const float*)d_in[20];
    const float* g2   = (const float*)d_in[21];
    const float* be2  = (const float*)d_in[22];
    const float* mW1  = (const float*)d_in[23];
    const float* mb1  = (const float*)d_in[24];
    const float* mW2  = (const float*)d_in[25];
    const float* mb2  = (const float*)d_in[26];
    float* outp = (float*)d_out;

    size_t off = 0;
    auto carve = [&](size_t bytes) -> void* {
        void* p = (char*)d_ws + off;
        off = (off + bytes + 255) & ~(size_t)255;
        return p;
    };
    f16* big1 = (f16*)carve((size_t)NN*W3P*2);          // h / y buffers
    f16* big2 = (f16*)carve((size_t)NN*W3P*2);          // hp buffer
    f16* Wt   = (f16*)carve((size_t)W3*W3P*2);          // transposed (scaled) weights
    float* a_s   = (float*)carve((size_t)NN*3*4);
    float* a_d   = (float*)carve((size_t)NN*3*4);
    float* psum  = (float*)carve((size_t)2*W3*4);
    float* psq   = psum + W3;
    float* mu    = (float*)carve((size_t)W3*4);
    float* istd  = (float*)carve((size_t)W3*4);
    float* sc    = (float*)carve((size_t)W3*4);
    float* sh    = (float*)carve((size_t)W3*4);
    float* dvec  = (float*)carve((size_t)W3*4);
    float* pooled= (float*)carve((size_t)NGR*EMB*4);
    int*   grp   = (int*)carve((size_t)(NGR+1)*4);
    int*   deg   = (int*)carve((size_t)NN*4);
    int*   rp    = (int*)carve((size_t)(NN+1)*4);
    int*   csrc  = (int*)carve((size_t)ELP*4);

    if (ws_size < off) return;

    // CSR build
    k_zero_i32<<<cdiv_i(NN,256),256,0,stream>>>(deg, NN);
    k_deg<<<cdiv_i(ELP,256),256,0,stream>>>(ei, deg);
    k_scan<<<1,1024,0,stream>>>(deg, rp);
    k_copy_i32<<<cdiv_i(NN,256),256,0,stream>>>(rp, deg, NN);
    k_fill<<<cdiv_i(ELP,256),256,0,stream>>>(ei, deg, csrc);
    k_grp<<<1,256,0,stream>>>(batch, grp);

    // h0
    k_build_h<<<cdiv_i((long long)NN*EMBP,256),256,0,stream>>>(x, tW, tb, big1);
    k_zero_f32<<<cdiv_i(W3,256),256,0,stream>>>(dvec, W3);   // layer 0: no BN fold

    struct Layer { const float* W; const float* as; const float* ad; const float* b;
                   const float* g; const float* be; int H; int K; int KP; };
    Layer layers[3] = {
        {W0, as0, ad0, b0, g0, be0, 3, EMB, EMBP},
        {W1, as1, ad1, b1, g1, be1, 3, W3,  W3P },
        {W2, as2, ad2, b2, g2, be2, 1, W3,  W3P },
    };

    for (int L = 0; L < 3; L++){
        Layer& ly = layers[L];
        int Wout  = ly.H * EMB;                 // 2340 / 2340 / 780
        int SPout = (Wout == W3) ? W3P : EMBP;  // 2368 / 2368 / 800
        const float* scale = (L == 0) ? nullptr : sc;

        // Wt <- W^T (scaled by previous layer's BN scale); dvec <- sh @ W (L>0)
        dim3 tg(cdiv_i(Wout,32), cdiv_i(ly.KP,32));
        k_transpose<<<tg, dim3(32,8), 0, stream>>>(ly.W, Wt, scale, ly.K, Wout, ly.KP);
        if (L > 0)
            k_dvec<<<cdiv_i(Wout,256),256,0,stream>>>(ly.W, sh, dvec, ly.K, Wout);

        // hp = BN(h) @ W via f16 MFMA (BN folded), XCD-pinned strips
        int Mtiles = cdiv_i(NN,128), NT = cdiv_i(Wout,128);
        int nb = ((Mtiles+7)/8)*8*NT;
        k_gemm_mfma<<<nb, 256, 0, stream>>>(big1, Wt, dvec, big2, NN, Wout, ly.KP, SPout, Mtiles, NT);

        // attention coefficients
        k_att<<<NN, ly.H*64, 0, stream>>>(big2, ly.as, ly.ad, a_s, a_d, ly.H, SPout);

        // softmax + aggregate + bias + tanh -> big1 (pre-BN y, pads zeroed)
        k_agg<<<NN,256,0,stream>>>(big2, rp, csrc, a_s, a_d, ly.b, big1, ly.H, SPout, Wout);

        // BN stats + fold coefficients
        k_zero_f32<<<cdiv_i(2*W3,256),256,0,stream>>>(psum, 2*W3);
        dim3 gs(cdiv_i(Wout/4,256), 64);
        k_bnstat<<<gs,256,0,stream>>>(big1, psum, psq, Wout, SPout);
        k_bnfin<<<cdiv_i(Wout,256),256,0,stream>>>(psum, psq, ly.g, ly.be, mu, istd, sc, sh, Wout);
    }

    // final layer BN applied explicitly (feeds pooling)
    k_bnapply<<<cdiv_i((long long)NN*(EMB/4),256),256,0,stream>>>(big1, sc, sh, EMB, EMBP);

    // segmented pooling + MLP
    dim3 pg(NGR, cdiv_i(EMB,256));
    k_pool<<<pg,256,0,stream>>>(big1, grp, pooled);
    k_mlp<<<NGR,256,0,stream>>>(pooled, grp, mW1, mb1, mW2, mb2, outp);
}

// Round 5
// 1839.632 us; speedup vs baseline: 1.5747x; 1.5747x over previous
//
#include <hip/hip_runtime.h>
#include <math.h>

#define NN   20000
#define EE   80000
#define ELP  100000   // EE + NN self loops
#define NGR  64
#define EMB  780
#define W3   2340
#define EMBP 800      // 780 padded to mult of 32
#define W3P  2368     // 2340 padded to mult of 32

static inline int cdiv_i(long long a, long long b){ return (int)((a + b - 1) / b); }

typedef _Float16 f16;
typedef _Float16 f16x2 __attribute__((ext_vector_type(2)));
typedef _Float16 f16x4 __attribute__((ext_vector_type(4)));
typedef _Float16 f16x8 __attribute__((ext_vector_type(8)));
typedef float    f32x4 __attribute__((ext_vector_type(4)));

__device__ __forceinline__ void async_ld16(const f16* g, f16* l){
    __builtin_amdgcn_global_load_lds(
        (const __attribute__((address_space(1))) unsigned int*)g,
        (__attribute__((address_space(3))) unsigned int*)l,
        16, 0, 0);
}

// ---------------- utility kernels ----------------
__global__ void k_zero_f32(float* p, int n){
    int i = blockIdx.x*256 + threadIdx.x; if (i < n) p[i] = 0.f;
}
__global__ void k_zero_i32(int* p, int n){
    int i = blockIdx.x*256 + threadIdx.x; if (i < n) p[i] = 0;
}
__global__ void k_copy_i32(const int* __restrict__ s, int* __restrict__ d, int n){
    int i = blockIdx.x*256 + threadIdx.x; if (i < n) d[i] = s[i];
}

// W [K,N] fp32 -> Wt [N,KP] f16, optional per-k scale (BN fold), pad k zeroed
__global__ void k_transpose(const float* __restrict__ W, f16* __restrict__ Wt,
                            const float* __restrict__ sc, int K, int N, int KP){
    __shared__ float T[32][33];
    int n0 = blockIdx.x*32, k0 = blockIdx.y*32;
    int tx = threadIdx.x, ty = threadIdx.y;   // 32 x 8
#pragma unroll
    for (int r = 0; r < 4; r++){
        int k = k0 + ty + r*8;
        float v = 0.f;
        if (k < K && n0 + tx < N){
            v = W[(size_t)k*N + n0 + tx];
            if (sc) v *= sc[k];
        }
        T[ty + r*8][tx] = v;
    }
    __syncthreads();
#pragma unroll
    for (int r = 0; r < 4; r++){
        int n = n0 + ty + r*8;
        int k = k0 + tx;
        if (n < N && k < KP) Wt[(size_t)n*KP + k] = (f16)T[tx][ty + r*8];
    }
}

// dvec[n] += sum_{k in slice} sh[k] * W[k,n]  — coalesced, K split across blockIdx.y
#define DVEC_KSPLIT 32
__global__ void k_dvec(const float* __restrict__ W, const float* __restrict__ sh,
                       float* __restrict__ dvec, int K, int N){
    int n = blockIdx.x*256 + threadIdx.x;
    if (n >= N) return;
    int slice = blockIdx.y;
    int k0 = (int)(((long long)K * slice) / DVEC_KSPLIT);
    int k1 = (int)(((long long)K * (slice+1)) / DVEC_KSPLIT);
    float s = 0.f;
    for (int k = k0; k < k1; k++) s += sh[k] * W[(size_t)k*N + n];
    atomicAdd(&dvec[n], s);
}

// ---------------- h0 ----------------
__global__ void k_build_h(const float* __restrict__ x, const float* __restrict__ tW,
                          const float* __restrict__ tb, f16* __restrict__ h){
    int idx = blockIdx.x*256 + threadIdx.x;
    if (idx >= NN*EMBP) return;
    int n = idx / EMBP, c = idx - n*EMBP;
    const float* xr = x + (size_t)n*772;
    float v;
    if (c < 768) v = xr[c];
    else if (c < EMB){
        int j = c - 768;
        v = tb[j] + xr[768]*tW[j] + xr[769]*tW[12+j] + xr[770]*tW[24+j] + xr[771]*tW[36+j];
    } else v = 0.f;
    h[idx] = (f16)v;
}

// ---------------- CSR build ----------------
__global__ void k_deg(const int* __restrict__ ei, int* __restrict__ deg){
    int k = blockIdx.x*256 + threadIdx.x; if (k >= ELP) return;
    int d = (k < EE) ? ei[EE + k] : (k - EE);
    atomicAdd(&deg[d], 1);
}

__global__ __launch_bounds__(1024) void k_scan(const int* __restrict__ deg, int* __restrict__ rp){
    __shared__ int buf[1024];
    __shared__ int carry;
    int tid = threadIdx.x;
    if (tid == 0){ carry = 0; rp[0] = 0; }
    __syncthreads();
    for (int base = 0; base < NN; base += 1024){
        int i = base + tid;
        int v = (i < NN) ? deg[i] : 0;
        buf[tid] = v; __syncthreads();
        for (int off = 1; off < 1024; off <<= 1){
            int t = (tid >= off) ? buf[tid-off] : 0;
            __syncthreads();
            buf[tid] += t;
            __syncthreads();
        }
        int incl = buf[tid];
        int tot  = buf[1023];
        if (i < NN) rp[i+1] = carry + incl;
        __syncthreads();
        if (tid == 0) carry += tot;
        __syncthreads();
    }
}

__global__ void k_fill(const int* __restrict__ ei, int* __restrict__ cursor, int* __restrict__ csrc){
    int k = blockIdx.x*256 + threadIdx.x; if (k >= ELP) return;
    int s, d;
    if (k < EE){ s = ei[k]; d = ei[EE + k]; } else { s = k - EE; d = s; }
    int pos = atomicAdd(&cursor[d], 1);
    csrc[pos] = s;
}

// graph ranges from sorted batch: grp[g] = first idx with batch[idx] >= g
__global__ void k_grp(const int* __restrict__ batch, int* __restrict__ grp){
    int g = blockIdx.x*256 + threadIdx.x; if (g > NGR) return;
    int lo = 0, hi = NN;
    while (lo < hi){ int mid = (lo+hi)>>1; if (batch[mid] < g) lo = mid+1; else hi = mid; }
    grp[g] = lo;
}

// ---------------- MFMA f16 GEMM, XCD-pinned strips: C = A[M,KP] @ Bt[N,KP]^T + dvec ----------
__global__ __launch_bounds__(256) void k_gemm_mfma(const f16* __restrict__ A,
                                                   const f16* __restrict__ Bt,
                                                   const float* __restrict__ dvec,
                                                   f16* __restrict__ C,
                                                   int M, int N, int KP, int SN,
                                                   int Mtiles, int NT){
    // decode: all NT n-tiles of one m-strip run on the same XCD (bid%8)
    int bid = blockIdx.x;
    int xcd = bid & 7;
    int j   = bid >> 3;
    int sl  = j / NT;
    int nt  = j - sl*NT;
    int mt  = sl*8 + xcd;
    if (mt >= Mtiles) return;
    int m0 = mt*128, n0 = nt*128;

    __shared__ f16 As[128*32];
    __shared__ f16 Bs[128*32];
    int tid = threadIdx.x;
    int w = tid >> 6, lane = tid & 63;

    int lrow = lane >> 2;
    int lko  = (lane & 3) * 8;

    int i2a = w*2, i2b = w*2 + 1;
    const f16* gA0 = A  + (size_t)min(m0 + i2a*16 + lrow, M-1)*KP + lko;
    const f16* gA1 = A  + (size_t)min(m0 + i2b*16 + lrow, M-1)*KP + lko;
    const f16* gB0 = Bt + (size_t)min(n0 + i2a*16 + lrow, N-1)*KP + lko;
    const f16* gB1 = Bt + (size_t)min(n0 + i2b*16 + lrow, N-1)*KP + lko;
    f16* lA0 = &As[i2a*512]; f16* lA1 = &As[i2b*512];
    f16* lB0 = &Bs[i2a*512]; f16* lB1 = &Bs[i2b*512];

    f32x4 acc[4][4];
#pragma unroll
    for (int i = 0; i < 4; i++)
#pragma unroll
        for (int j2 = 0; j2 < 4; j2++) acc[i][j2] = (f32x4)0.f;

    int wm = (w & 1) * 64, wn = (w >> 1) * 64;
    int lq = lane >> 4, lm = lane & 15;

    for (int kk = 0; kk < KP; kk += 32){
        __syncthreads();
        async_ld16(gA0 + kk, lA0);
        async_ld16(gA1 + kk, lA1);
        async_ld16(gB0 + kk, lB0);
        async_ld16(gB1 + kk, lB1);
        __syncthreads();

        f16x8 aF[4], bF[4];
#pragma unroll
        for (int mi = 0; mi < 4; mi++)
            aF[mi] = *(const f16x8*)&As[(wm + mi*16 + lm)*32 + lq*8];
#pragma unroll
        for (int ni = 0; ni < 4; ni++)
            bF[ni] = *(const f16x8*)&Bs[(wn + ni*16 + lm)*32 + lq*8];
#pragma unroll
        for (int mi = 0; mi < 4; mi++)
#pragma unroll
            for (int ni = 0; ni < 4; ni++)
                acc[mi][ni] = __builtin_amdgcn_mfma_f32_16x16x32_f16(aF[mi], bF[ni], acc[mi][ni], 0, 0, 0);
    }

#pragma unroll
    for (int mi = 0; mi < 4; mi++){
#pragma unroll
        for (int ni = 0; ni < 4; ni++){
            int col = n0 + wn + ni*16 + lm;
            if (col < SN){
                float dv = (col < N) ? dvec[col] : 0.f;
                int rbase = m0 + wm + mi*16 + lq*4;
#pragma unroll
                for (int r = 0; r < 4; r++){
                    int row = rbase + r;
                    if (row < M){
                        float v = (col < N) ? (acc[mi][ni][r] + dv) : 0.f;
                        C[(size_t)row*SN + col] = (f16)v;
                    }
                }
            }
        }
    }
}

// ---------------- attention coefficients ----------------
__global__ void k_att(const f16* __restrict__ hp, const float* __restrict__ asrc,
                      const float* __restrict__ adst, float* __restrict__ a_s,
                      float* __restrict__ a_d, int H, int SP){
    int n = blockIdx.x;
    int wv = threadIdx.x >> 6, lane = threadIdx.x & 63;
    const f16* row = hp + (size_t)n*SP + wv*EMB;
    const float* pa = asrc + wv*EMB;
    const float* pd = adst + wv*EMB;
    float s = 0.f, d = 0.f;
    for (int c = lane; c < EMB; c += 64){ float v = (float)row[c]; s += v*pa[c]; d += v*pd[c]; }
#pragma unroll
    for (int off = 32; off; off >>= 1){ s += __shfl_xor(s, off); d += __shfl_xor(d, off); }
    if (lane == 0){ a_s[n*H + wv] = s; a_d[n*H + wv] = d; }
}

// ---------------- per-dst softmax + aggregation + bias + tanh (f16x4 cols) ----------------
__global__ __launch_bounds__(256) void k_agg(const f16* __restrict__ hp, const int* __restrict__ rp,
                                             const int* __restrict__ csrc, const float* __restrict__ a_s,
                                             const float* __restrict__ a_d, const float* __restrict__ bias,
                                             f16* __restrict__ y, int H, int SP, int W){
    int n = blockIdx.x, tid = threadIdx.x;
    int beg = rp[n], deg = rp[n+1] - beg;

    __shared__ float sm[3], sden[3];
    __shared__ float sal[64*3];
    __shared__ int   ssrc[64];

    if (tid < 64){
        float adn[3];
#pragma unroll
        for (int h = 0; h < 3; h++) adn[h] = (h < H) ? a_d[n*H + h] : 0.f;
        float mx[3] = {-1e30f, -1e30f, -1e30f};
        for (int e = tid; e < deg; e += 64){
            int s = csrc[beg + e];
#pragma unroll
            for (int h = 0; h < 3; h++) if (h < H){
                float v = a_s[s*H + h] + adn[h];
                v = v > 0.f ? v : 0.2f*v;
                mx[h] = fmaxf(mx[h], v);
            }
        }
#pragma unroll
        for (int off = 32; off; off >>= 1){
#pragma unroll
            for (int h = 0; h < 3; h++) mx[h] = fmaxf(mx[h], __shfl_xor(mx[h], off));
        }
        float dn[3] = {0.f, 0.f, 0.f};
        for (int e = tid; e < deg; e += 64){
            int s = csrc[beg + e];
#pragma unroll
            for (int h = 0; h < 3; h++) if (h < H){
                float v = a_s[s*H + h] + adn[h];
                v = v > 0.f ? v : 0.2f*v;
                dn[h] += expf(v - mx[h]);
            }
        }
#pragma unroll
        for (int off = 32; off; off >>= 1){
#pragma unroll
            for (int h = 0; h < 3; h++) dn[h] += __shfl_xor(dn[h], off);
        }
        if (tid == 0){
#pragma unroll
            for (int h = 0; h < 3; h++){ sm[h] = mx[h]; sden[h] = dn[h]; }
        }
    }
    __syncthreads();

    float4 acc4[3];
    int c4[3], hh4[3];
#pragma unroll
    for (int i = 0; i < 3; i++){
        acc4[i] = make_float4(0.f,0.f,0.f,0.f);
        c4[i] = tid*4 + i*1024;
        hh4[i] = (c4[i] < W) ? (c4[i] / EMB) : 0;   // 780 % 4 == 0: quads never straddle heads
    }

    for (int base = 0; base < deg; base += 64){
        int cnt = min(64, deg - base);
        if (tid < cnt) ssrc[tid] = csrc[beg + base + tid];
        if (tid < cnt*H){
            int e = tid / H, h = tid - e*H;
            int s = csrc[beg + base + e];
            float v = a_s[s*H + h] + a_d[n*H + h];
            v = v > 0.f ? v : 0.2f*v;
            sal[e*3 + h] = expf(v - sm[h]) / (sden[h] + 1e-16f);
        }
        __syncthreads();
        for (int e = 0; e < cnt; e++){
            const f16* rowp = hp + (size_t)ssrc[e]*SP;
#pragma unroll
            for (int i = 0; i < 3; i++)
                if (c4[i] < W){
                    f16x4 v = *(const f16x4*)(rowp + c4[i]);
                    float al = sal[e*3 + hh4[i]];
                    acc4[i].x += al * (float)v[0];
                    acc4[i].y += al * (float)v[1];
                    acc4[i].z += al * (float)v[2];
                    acc4[i].w += al * (float)v[3];
                }
        }
        __syncthreads();
    }

#pragma unroll
    for (int i = 0; i < 3; i++){
        int c = c4[i];
        if (c < SP){
            f16x4 o;
            if (c < W){
                o[0] = (f16)tanhf(acc4[i].x + bias[c]);
                o[1] = (f16)tanhf(acc4[i].y + bias[c+1]);
                o[2] = (f16)tanhf(acc4[i].z + bias[c+2]);
                o[3] = (f16)tanhf(acc4[i].w + bias[c+3]);
            } else { o[0]=(f16)0.f; o[1]=(f16)0.f; o[2]=(f16)0.f; o[3]=(f16)0.f; }
            *(f16x4*)(y + (size_t)n*SP + c) = o;
        }
    }
}

// ---------------- BatchNorm stats (f16x4 loads) ----------------
__global__ void k_bnstat(const f16* __restrict__ y, float* __restrict__ psum,
                         float* __restrict__ psq, int W, int SP){
    int c0 = (blockIdx.x*256 + threadIdx.x)*4;
    if (c0 >= W) return;
    int slice = blockIdx.y;   // 0..63
    float s[4] = {0,0,0,0}, s2[4] = {0,0,0,0};
    for (int r = slice; r < NN; r += 64){
        f16x4 u = *(const f16x4*)(y + (size_t)r*SP + c0);
#pragma unroll
        for (int j = 0; j < 4; j++){ float v = (float)u[j]; s[j] += v; s2[j] += v*v; }
    }
#pragma unroll
    for (int j = 0; j < 4; j++){
        atomicAdd(&psum[c0+j], s[j]);
        atomicAdd(&psq[c0+j], s2[j]);
    }
}

// mu/istd + BN fold coefficients: sc = istd*gamma, sh = beta - mu*istd*gamma
__global__ void k_bnfin(const float* __restrict__ psum, const float* __restrict__ psq,
                        const float* __restrict__ gamma, const float* __restrict__ beta,
                        float* __restrict__ mu, float* __restrict__ istd,
                        float* __restrict__ sc, float* __restrict__ sh, int W){
    int c = blockIdx.x*256 + threadIdx.x; if (c >= W) return;
    float m = psum[c] * (1.f/NN);
    float v = psq[c] * (1.f/NN) - m*m;
    float is = 1.f / sqrtf(v + 1e-5f);
    mu[c] = m; istd[c] = is;
    float g = gamma[c];
    sc[c] = is * g;
    sh[c] = beta[c] - m * is * g;
}

// explicit BN apply (final layer only)
__global__ void k_bnapply(f16* __restrict__ y, const float* __restrict__ sc,
                          const float* __restrict__ sh, int W, int SP){
    int idx = blockIdx.x*256 + threadIdx.x;
    int w4 = W >> 2;
    if (idx >= NN * w4) return;
    int row = idx / w4;
    int c = (idx - row*w4) * 4;
    f16* p = y + (size_t)row*SP + c;
    f16x4 u = *(f16x4*)p;
#pragma unroll
    for (int j = 0; j < 4; j++)
        u[j] = (f16)((float)u[j] * sc[c+j] + sh[c+j]);
    *(f16x4*)p = u;
}

// ---------------- segmented pooling (batch sorted) + MLP ----------------
__global__ void k_pool(const f16* __restrict__ h, const int* __restrict__ grp,
                       float* __restrict__ pooled){
    int g = blockIdx.x;
    int c = blockIdx.y*256 + threadIdx.x;
    if (c >= EMB) return;
    int r0 = grp[g], r1 = grp[g+1];
    float s = 0.f;
    for (int r = r0; r < r1; r++) s += (float)h[(size_t)r*EMBP + c];
    pooled[g*EMB + c] = s;
}

__global__ __launch_bounds__(256) void k_mlp(const float* __restrict__ pooled, const int* __restrict__ grp,
                                             const float* __restrict__ W1, const float* __restrict__ b1,
                                             const float* __restrict__ W2, const float* __restrict__ b2,
                                             float* __restrict__ out){
    __shared__ float p[EMB];
    __shared__ float hid[128];
    int g = blockIdx.x, tid = threadIdx.x;
    int cnt = grp[g+1] - grp[g];
    float ic = 1.f / fmaxf((float)cnt, 1.f);
    for (int c = tid; c < EMB; c += 256){
        float v = pooled[g*EMB + c] * ic;
        p[c] = v > 0.f ? v : 0.f;
    }
    __syncthreads();
    if (tid < 128){
        float s = b1[tid];
        for (int k = 0; k < EMB; k++) s += p[k] * W1[k*128 + tid];
        hid[tid] = tanhf(s);
    }
    __syncthreads();
    if (tid < 64){
        float s = b2[tid];
        for (int k = 0; k < 128; k++) s += hid[k] * W2[k*64 + tid];
        out[g*64 + tid] = s;
    }
}

// ---------------- launch ----------------
extern "C" void kernel_launch(void* const* d_in, const int* in_sizes, int n_in,
                              void* d_out, int out_size, void* d_ws, size_t ws_size,
                              hipStream_t stream) {
    (void)in_sizes; (void)n_in; (void)out_size;
    const float* x    = (const float*)d_in[0];
    const int*   ei   = (const int*)  d_in[1];
    const int*   batch= (const int*)  d_in[2];
    const float* tW   = (const float*)d_in[3];
    const float* tb   = (const float*)d_in[4];
    const float* W0   = (const float*)d_in[5];
    const float* as0  = (const float*)d_in[6];
    const float* ad0  = (const float*)d_in[7];
    const float* b0   = (const float*)d_in[8];
    const float* g0   = (const float*)d_in[9];
    const float* be0  = (const float*)d_in[10];
    const float* W1   = (const float*)d_in[11];
    const float* as1  = (const float*)d_in[12];
    const float* ad1  = (const float*)d_in[13];
    const float* b1   = (const float*)d_in[14];
    const float* g1   = (const float*)d_in[15];
    const float* be1  = (const float*)d_in[16];
    const float* W2   = (const float*)d_in[17];
    const float* as2  = (const float*)d_in[18];
    const float* ad2  = (const float*)d_in[19];
    const float* b2   = (const float*)d_in[20];
    const float* g2   = (const float*)d_in[21];
    const float* be2  = (const float*)d_in[22];
    const float* mW1  = (const float*)d_in[23];
    const float* mb1  = (const float*)d_in[24];
    const float* mW2  = (const float*)d_in[25];
    const float* mb2  = (const float*)d_in[26];
    float* outp = (float*)d_out;

    size_t off = 0;
    auto carve = [&](size_t bytes) -> void* {
        void* p = (char*)d_ws + off;
        off = (off + bytes + 255) & ~(size_t)255;
        return p;
    };
    f16* big1 = (f16*)carve((size_t)NN*W3P*2);          // h / y buffers
    f16* big2 = (f16*)carve((size_t)NN*W3P*2);          // hp buffer
    f16* Wt   = (f16*)carve((size_t)W3*W3P*2);          // transposed (scaled) weights
    float* a_s   = (float*)carve((size_t)NN*3*4);
    float* a_d   = (float*)carve((size_t)NN*3*4);
    float* psum  = (float*)carve((size_t)2*W3*4);
    float* psq   = psum + W3;
    float* mu    = (float*)carve((size_t)W3*4);
    float* istd  = (float*)carve((size_t)W3*4);
    float* sc    = (float*)carve((size_t)W3*4);
    float* sh    = (float*)carve((size_t)W3*4);
    float* dvec  = (float*)carve((size_t)W3*4);
    float* pooled= (float*)carve((size_t)NGR*EMB*4);
    int*   grp   = (int*)carve((size_t)(NGR+1)*4);
    int*   deg   = (int*)carve((size_t)NN*4);
    int*   rp    = (int*)carve((size_t)(NN+1)*4);
    int*   csrc  = (int*)carve((size_t)ELP*4);

    if (ws_size < off) return;

    // CSR build
    k_zero_i32<<<cdiv_i(NN,256),256,0,stream>>>(deg, NN);
    k_deg<<<cdiv_i(ELP,256),256,0,stream>>>(ei, deg);
    k_scan<<<1,1024,0,stream>>>(deg, rp);
    k_copy_i32<<<cdiv_i(NN,256),256,0,stream>>>(rp, deg, NN);
    k_fill<<<cdiv_i(ELP,256),256,0,stream>>>(ei, deg, csrc);
    k_grp<<<1,256,0,stream>>>(batch, grp);

    // h0
    k_build_h<<<cdiv_i((long long)NN*EMBP,256),256,0,stream>>>(x, tW, tb, big1);

    struct Layer { const float* W; const float* as; const float* ad; const float* b;
                   const float* g; const float* be; int H; int K; int KP; };
    Layer layers[3] = {
        {W0, as0, ad0, b0, g0, be0, 3, EMB, EMBP},
        {W1, as1, ad1, b1, g1, be1, 3, W3,  W3P },
        {W2, as2, ad2, b2, g2, be2, 1, W3,  W3P },
    };

    for (int L = 0; L < 3; L++){
        Layer& ly = layers[L];
        int Wout  = ly.H * EMB;                 // 2340 / 2340 / 780
        int SPout = (Wout == W3) ? W3P : EMBP;  // 2368 / 2368 / 800
        const float* scale = (L == 0) ? nullptr : sc;

        // Wt <- W^T (scaled by previous layer's BN scale); dvec <- sh @ W (L>0, K-split coalesced)
        dim3 tg(cdiv_i(Wout,32), cdiv_i(ly.KP,32));
        k_transpose<<<tg, dim3(32,8), 0, stream>>>(ly.W, Wt, scale, ly.K, Wout, ly.KP);
        k_zero_f32<<<cdiv_i(W3,256),256,0,stream>>>(dvec, W3);
        if (L > 0){
            dim3 dg(cdiv_i(Wout,256), DVEC_KSPLIT);
            k_dvec<<<dg,256,0,stream>>>(ly.W, sh, dvec, ly.K, Wout);
        }

        // hp = BN(h) @ W via f16 MFMA (BN folded), XCD-pinned strips
        int Mtiles = cdiv_i(NN,128), NT = cdiv_i(Wout,128);
        int nb = ((Mtiles+7)/8)*8*NT;
        k_gemm_mfma<<<nb, 256, 0, stream>>>(big1, Wt, dvec, big2, NN, Wout, ly.KP, SPout, Mtiles, NT);

        // attention coefficients
        k_att<<<NN, ly.H*64, 0, stream>>>(big2, ly.as, ly.ad, a_s, a_d, ly.H, SPout);

        // softmax + aggregate + bias + tanh -> big1 (pre-BN y, pads zeroed)
        k_agg<<<NN,256,0,stream>>>(big2, rp, csrc, a_s, a_d, ly.b, big1, ly.H, SPout, Wout);

        // BN stats + fold coefficients
        k_zero_f32<<<cdiv_i(2*W3,256),256,0,stream>>>(psum, 2*W3);
        dim3 gs(cdiv_i(Wout/4,256), 64);
        k_bnstat<<<gs,256,0,stream>>>(big1, psum, psq, Wout, SPout);
        k_bnfin<<<cdiv_i(Wout,256),256,0,stream>>>(psum, psq, ly.g, ly.be, mu, istd, sc, sh, Wout);
    }

    // final layer BN applied explicitly (feeds pooling)
    k_bnapply<<<cdiv_i((long long)NN*(EMB/4),256),256,0,stream>>>(big1, sc, sh, EMB, EMBP);

    // segmented pooling + MLP
    dim3 pg(NGR, cdiv_i(EMB,256));
    k_pool<<<pg,256,0,stream>>>(big1, grp, pooled);
    k_mlp<<<NGR,256,0,stream>>>(pooled, grp, mW1, mb1, mW2, mb2, outp);
}

// Round 6
// 1667.277 us; speedup vs baseline: 1.7375x; 1.1034x over previous
//
#include <hip/hip_runtime.h>
#include <math.h>

#define NN   20000
#define EE   80000
#define ELP  100000   // EE + NN self loops
#define NGR  64
#define EMB  780
#define W3   2340
#define EMBP 832      // 780 padded to mult of 64 (BK)
#define W3P  2368     // 2340 padded to mult of 64

static inline int cdiv_i(long long a, long long b){ return (int)((a + b - 1) / b); }

typedef _Float16 f16;
typedef _Float16 f16x4 __attribute__((ext_vector_type(4)));
typedef _Float16 f16x8 __attribute__((ext_vector_type(8)));
typedef float    f32x4 __attribute__((ext_vector_type(4)));

__device__ __forceinline__ void async_ld16(const f16* g, f16* l){
    __builtin_amdgcn_global_load_lds(
        (const __attribute__((address_space(1))) unsigned int*)g,
        (__attribute__((address_space(3))) unsigned int*)l,
        16, 0, 0);
}

// ---------------- utility kernels ----------------
__global__ void k_zero_f32(float* p, int n){
    int i = blockIdx.x*256 + threadIdx.x; if (i < n) p[i] = 0.f;
}
__global__ void k_zero_i32(int* p, int n){
    int i = blockIdx.x*256 + threadIdx.x; if (i < n) p[i] = 0;
}
__global__ void k_copy_i32(const int* __restrict__ s, int* __restrict__ d, int n){
    int i = blockIdx.x*256 + threadIdx.x; if (i < n) d[i] = s[i];
}

// W [K,N] fp32 -> Wt [N,KP] f16, optional per-k scale (BN fold), pad k zeroed
__global__ void k_transpose(const float* __restrict__ W, f16* __restrict__ Wt,
                            const float* __restrict__ sc, int K, int N, int KP){
    __shared__ float T[32][33];
    int n0 = blockIdx.x*32, k0 = blockIdx.y*32;
    int tx = threadIdx.x, ty = threadIdx.y;   // 32 x 8
#pragma unroll
    for (int r = 0; r < 4; r++){
        int k = k0 + ty + r*8;
        float v = 0.f;
        if (k < K && n0 + tx < N){
            v = W[(size_t)k*N + n0 + tx];
            if (sc) v *= sc[k];
        }
        T[ty + r*8][tx] = v;
    }
    __syncthreads();
#pragma unroll
    for (int r = 0; r < 4; r++){
        int n = n0 + ty + r*8;
        int k = k0 + tx;
        if (n < N && k < KP) Wt[(size_t)n*KP + k] = (f16)T[tx][ty + r*8];
    }
}

// dvec[n] += sum_{k in slice} sh[k] * W[k,n]  — coalesced, K split across blockIdx.y
#define DVEC_KSPLIT 32
__global__ void k_dvec(const float* __restrict__ W, const float* __restrict__ sh,
                       float* __restrict__ dvec, int K, int N){
    int n = blockIdx.x*256 + threadIdx.x;
    if (n >= N) return;
    int slice = blockIdx.y;
    int k0 = (int)(((long long)K * slice) / DVEC_KSPLIT);
    int k1 = (int)(((long long)K * (slice+1)) / DVEC_KSPLIT);
    float s = 0.f;
    for (int k = k0; k < k1; k++) s += sh[k] * W[(size_t)k*N + n];
    atomicAdd(&dvec[n], s);
}

// ---------------- h0 ----------------
__global__ void k_build_h(const float* __restrict__ x, const float* __restrict__ tW,
                          const float* __restrict__ tb, f16* __restrict__ h){
    int idx = blockIdx.x*256 + threadIdx.x;
    if (idx >= NN*EMBP) return;
    int n = idx / EMBP, c = idx - n*EMBP;
    const float* xr = x + (size_t)n*772;
    float v;
    if (c < 768) v = xr[c];
    else if (c < EMB){
        int j = c - 768;
        v = tb[j] + xr[768]*tW[j] + xr[769]*tW[12+j] + xr[770]*tW[24+j] + xr[771]*tW[36+j];
    } else v = 0.f;
    h[idx] = (f16)v;
}

// ---------------- CSR build ----------------
__global__ void k_deg(const int* __restrict__ ei, int* __restrict__ deg){
    int k = blockIdx.x*256 + threadIdx.x; if (k >= ELP) return;
    int d = (k < EE) ? ei[EE + k] : (k - EE);
    atomicAdd(&deg[d], 1);
}

// 20 nodes/thread local sum -> single 1024-scan -> write prefixes
__global__ __launch_bounds__(1024) void k_scan(const int* __restrict__ deg, int* __restrict__ rp){
    __shared__ int part[1024];
    int tid = threadIdx.x;
    int i0 = tid*20;
    int n = (i0 < NN) ? min(20, NN - i0) : 0;
    int s = 0;
    for (int k = 0; k < n; k++) s += deg[i0+k];
    part[tid] = s; __syncthreads();
    for (int off = 1; off < 1024; off <<= 1){
        int t = (tid >= off) ? part[tid-off] : 0;
        __syncthreads();
        part[tid] += t;
        __syncthreads();
    }
    int run = part[tid] - s;   // exclusive prefix
    for (int k = 0; k < n; k++){ rp[i0+k] = run; run += deg[i0+k]; }
    if (tid == 1023) rp[NN] = part[1023];
}

__global__ void k_fill(const int* __restrict__ ei, int* __restrict__ cursor, int* __restrict__ csrc){
    int k = blockIdx.x*256 + threadIdx.x; if (k >= ELP) return;
    int s, d;
    if (k < EE){ s = ei[k]; d = ei[EE + k]; } else { s = k - EE; d = s; }
    int pos = atomicAdd(&cursor[d], 1);
    csrc[pos] = s;
}

// graph ranges from sorted batch
__global__ void k_grp(const int* __restrict__ batch, int* __restrict__ grp){
    int g = blockIdx.x*256 + threadIdx.x; if (g > NGR) return;
    int lo = 0, hi = NN;
    while (lo < hi){ int mid = (lo+hi)>>1; if (batch[mid] < g) lo = mid+1; else hi = mid; }
    grp[g] = lo;
}

// ------ MFMA f16 GEMM, XCD-pinned strips, BK=64 (two 32-K panels per barrier pair) ------
__global__ __launch_bounds__(256) void k_gemm_mfma(const f16* __restrict__ A,
                                                   const f16* __restrict__ Bt,
                                                   const float* __restrict__ dvec,
                                                   f16* __restrict__ C,
                                                   int M, int N, int KP, int SN,
                                                   int Mtiles, int NT){
    int bid = blockIdx.x;
    int xcd = bid & 7;
    int j   = bid >> 3;
    int sl  = j / NT;
    int nt  = j - sl*NT;
    int mt  = sl*8 + xcd;
    if (mt >= Mtiles) return;
    int m0 = mt*128, n0 = nt*128;

    __shared__ f16 As[128*64];   // two 128x32 panels
    __shared__ f16 Bs[128*64];
    int tid = threadIdx.x;
    int w = tid >> 6, lane = tid & 63;

    int lrow = lane >> 2;
    int lko  = (lane & 3) * 8;

    int i2a = w*2, i2b = w*2 + 1;
    const f16* gA0 = A  + (size_t)min(m0 + i2a*16 + lrow, M-1)*KP + lko;
    const f16* gA1 = A  + (size_t)min(m0 + i2b*16 + lrow, M-1)*KP + lko;
    const f16* gB0 = Bt + (size_t)min(n0 + i2a*16 + lrow, N-1)*KP + lko;
    const f16* gB1 = Bt + (size_t)min(n0 + i2b*16 + lrow, N-1)*KP + lko;
    f16* lA0 = &As[i2a*512]; f16* lA1 = &As[i2b*512];
    f16* lB0 = &Bs[i2a*512]; f16* lB1 = &Bs[i2b*512];

    f32x4 acc[4][4];
#pragma unroll
    for (int i = 0; i < 4; i++)
#pragma unroll
        for (int j2 = 0; j2 < 4; j2++) acc[i][j2] = (f32x4)0.f;

    int wm = (w & 1) * 64, wn = (w >> 1) * 64;
    int lq = lane >> 4, lm = lane & 15;

    for (int kk = 0; kk < KP; kk += 64){
        __syncthreads();
        async_ld16(gA0 + kk, lA0);
        async_ld16(gA1 + kk, lA1);
        async_ld16(gB0 + kk, lB0);
        async_ld16(gB1 + kk, lB1);
        async_ld16(gA0 + kk + 32, lA0 + 4096);
        async_ld16(gA1 + kk + 32, lA1 + 4096);
        async_ld16(gB0 + kk + 32, lB0 + 4096);
        async_ld16(gB1 + kk + 32, lB1 + 4096);
        __syncthreads();

#pragma unroll
        for (int half = 0; half < 2; half++){
            const f16* Ap = As + half*4096;
            const f16* Bp = Bs + half*4096;
            f16x8 aF[4], bF[4];
#pragma unroll
            for (int mi = 0; mi < 4; mi++)
                aF[mi] = *(const f16x8*)&Ap[(wm + mi*16 + lm)*32 + lq*8];
#pragma unroll
            for (int ni = 0; ni < 4; ni++)
                bF[ni] = *(const f16x8*)&Bp[(wn + ni*16 + lm)*32 + lq*8];
#pragma unroll
            for (int mi = 0; mi < 4; mi++)
#pragma unroll
                for (int ni = 0; ni < 4; ni++)
                    acc[mi][ni] = __builtin_amdgcn_mfma_f32_16x16x32_f16(aF[mi], bF[ni], acc[mi][ni], 0, 0, 0);
        }
    }

#pragma unroll
    for (int mi = 0; mi < 4; mi++){
#pragma unroll
        for (int ni = 0; ni < 4; ni++){
            int col = n0 + wn + ni*16 + lm;
            if (col < SN){
                float dv = (col < N) ? dvec[col] : 0.f;
                int rbase = m0 + wm + mi*16 + lq*4;
#pragma unroll
                for (int r = 0; r < 4; r++){
                    int row = rbase + r;
                    if (row < M){
                        float v = (col < N) ? (acc[mi][ni][r] + dv) : 0.f;
                        C[(size_t)row*SN + col] = (f16)v;
                    }
                }
            }
        }
    }
}

// ---------------- attention coefficients (f16x4 loads) ----------------
__global__ void k_att(const f16* __restrict__ hp, const float* __restrict__ asrc,
                      const float* __restrict__ adst, float* __restrict__ a_s,
                      float* __restrict__ a_d, int H, int SP){
    int n = blockIdx.x;
    int wv = threadIdx.x >> 6, lane = threadIdx.x & 63;
    const f16* row = hp + (size_t)n*SP + wv*EMB;
    const float* pa = asrc + wv*EMB;
    const float* pd = adst + wv*EMB;
    float s = 0.f, d = 0.f;
    for (int c = lane*4; c < EMB; c += 256){
        f16x4 v = *(const f16x4*)(row + c);
#pragma unroll
        for (int jj = 0; jj < 4; jj++){
            float f = (float)v[jj];
            s += f*pa[c+jj]; d += f*pd[c+jj];
        }
    }
#pragma unroll
    for (int off = 32; off; off >>= 1){ s += __shfl_xor(s, off); d += __shfl_xor(d, off); }
    if (lane == 0){ a_s[n*H + wv] = s; a_d[n*H + wv] = d; }
}

// ---------------- per-dst softmax + aggregation + bias + tanh ----------------
__global__ __launch_bounds__(256) void k_agg(const f16* __restrict__ hp, const int* __restrict__ rp,
                                             const int* __restrict__ csrc, const float* __restrict__ a_s,
                                             const float* __restrict__ a_d, const float* __restrict__ bias,
                                             f16* __restrict__ y, int H, int SP, int W){
    int n = blockIdx.x, tid = threadIdx.x;
    int beg = rp[n], deg = rp[n+1] - beg;

    __shared__ float sm[3], sden[3];
    __shared__ float sal[64*3];
    __shared__ int   ssrc[64];

    if (tid < 64){
        float adn[3];
#pragma unroll
        for (int h = 0; h < 3; h++) adn[h] = (h < H) ? a_d[n*H + h] : 0.f;
        float mx[3] = {-1e30f, -1e30f, -1e30f};
        for (int e = tid; e < deg; e += 64){
            int s = csrc[beg + e];
#pragma unroll
            for (int h = 0; h < 3; h++) if (h < H){
                float v = a_s[s*H + h] + adn[h];
                v = v > 0.f ? v : 0.2f*v;
                mx[h] = fmaxf(mx[h], v);
            }
        }
#pragma unroll
        for (int off = 32; off; off >>= 1){
#pragma unroll
            for (int h = 0; h < 3; h++) mx[h] = fmaxf(mx[h], __shfl_xor(mx[h], off));
        }
        float dn[3] = {0.f, 0.f, 0.f};
        for (int e = tid; e < deg; e += 64){
            int s = csrc[beg + e];
#pragma unroll
            for (int h = 0; h < 3; h++) if (h < H){
                float v = a_s[s*H + h] + adn[h];
                v = v > 0.f ? v : 0.2f*v;
                dn[h] += expf(v - mx[h]);
            }
        }
#pragma unroll
        for (int off = 32; off; off >>= 1){
#pragma unroll
            for (int h = 0; h < 3; h++) dn[h] += __shfl_xor(dn[h], off);
        }
        if (tid == 0){
#pragma unroll
            for (int h = 0; h < 3; h++){ sm[h] = mx[h]; sden[h] = dn[h]; }
        }
    }
    __syncthreads();

    float4 acc4[3];
    int c4[3], hh4[3];
#pragma unroll
    for (int i = 0; i < 3; i++){
        acc4[i] = make_float4(0.f,0.f,0.f,0.f);
        c4[i] = tid*4 + i*1024;
        hh4[i] = (c4[i] < W) ? (c4[i] / EMB) : 0;   // 780 % 4 == 0: quads never straddle heads
    }

    for (int base = 0; base < deg; base += 64){
        int cnt = min(64, deg - base);
        if (tid < cnt) ssrc[tid] = csrc[beg + base + tid];
        if (tid < cnt*H){
            int e = tid / H, h = tid - e*H;
            int s = csrc[beg + base + e];
            float v = a_s[s*H + h] + a_d[n*H + h];
            v = v > 0.f ? v : 0.2f*v;
            sal[e*3 + h] = expf(v - sm[h]) / (sden[h] + 1e-16f);
        }
        __syncthreads();
        int e = 0;
        for (; e + 2 <= cnt; e += 2){
            const f16* r0 = hp + (size_t)ssrc[e]*SP;
            const f16* r1 = hp + (size_t)ssrc[e+1]*SP;
            f16x4 va[3], vb[3];
#pragma unroll
            for (int i = 0; i < 3; i++)
                if (c4[i] < W){
                    va[i] = *(const f16x4*)(r0 + c4[i]);
                    vb[i] = *(const f16x4*)(r1 + c4[i]);
                }
#pragma unroll
            for (int i = 0; i < 3; i++)
                if (c4[i] < W){
                    float a0 = sal[e*3 + hh4[i]], a1 = sal[(e+1)*3 + hh4[i]];
                    acc4[i].x += a0*(float)va[i][0] + a1*(float)vb[i][0];
                    acc4[i].y += a0*(float)va[i][1] + a1*(float)vb[i][1];
                    acc4[i].z += a0*(float)va[i][2] + a1*(float)vb[i][2];
                    acc4[i].w += a0*(float)va[i][3] + a1*(float)vb[i][3];
                }
        }
        if (e < cnt){
            const f16* r0 = hp + (size_t)ssrc[e]*SP;
#pragma unroll
            for (int i = 0; i < 3; i++)
                if (c4[i] < W){
                    f16x4 v = *(const f16x4*)(r0 + c4[i]);
                    float al = sal[e*3 + hh4[i]];
                    acc4[i].x += al*(float)v[0];
                    acc4[i].y += al*(float)v[1];
                    acc4[i].z += al*(float)v[2];
                    acc4[i].w += al*(float)v[3];
                }
        }
        __syncthreads();
    }

#pragma unroll
    for (int i = 0; i < 3; i++){
        int c = c4[i];
        if (c < SP){
            f16x4 o;
            if (c < W){
                o[0] = (f16)tanhf(acc4[i].x + bias[c]);
                o[1] = (f16)tanhf(acc4[i].y + bias[c+1]);
                o[2] = (f16)tanhf(acc4[i].z + bias[c+2]);
                o[3] = (f16)tanhf(acc4[i].w + bias[c+3]);
            } else { o[0]=(f16)0.f; o[1]=(f16)0.f; o[2]=(f16)0.f; o[3]=(f16)0.f; }
            *(f16x4*)(y + (size_t)n*SP + c) = o;
        }
    }
}

// ---------------- BatchNorm stats: partial sums per slice (no atomics) ----------------
__global__ void k_bnstat(const f16* __restrict__ y, float* __restrict__ ps,
                         float* __restrict__ pq, int W, int SP){
    int c0 = (blockIdx.x*256 + threadIdx.x)*4;
    if (c0 >= W) return;
    int slice = blockIdx.y;   // 0..63
    float s[4] = {0,0,0,0}, q[4] = {0,0,0,0};
    for (int r = slice; r < NN; r += 64){
        f16x4 u = *(const f16x4*)(y + (size_t)r*SP + c0);
#pragma unroll
        for (int j = 0; j < 4; j++){ float v = (float)u[j]; s[j] += v; q[j] += v*v; }
    }
#pragma unroll
    for (int j = 0; j < 4; j++){
        ps[(size_t)slice*W3 + c0+j] = s[j];
        pq[(size_t)slice*W3 + c0+j] = q[j];
    }
}

// reduce partials; sc = istd*gamma, sh = beta - mu*istd*gamma
__global__ void k_bnfin(const float* __restrict__ ps, const float* __restrict__ pq,
                        const float* __restrict__ gamma, const float* __restrict__ beta,
                        float* __restrict__ sc, float* __restrict__ sh, int W){
    int c = blockIdx.x*256 + threadIdx.x; if (c >= W) return;
    float m = 0.f, q = 0.f;
    for (int s = 0; s < 64; s++){ m += ps[(size_t)s*W3 + c]; q += pq[(size_t)s*W3 + c]; }
    m *= (1.f/NN);
    float v = q * (1.f/NN) - m*m;
    float is = 1.f / sqrtf(v + 1e-5f);
    float g = gamma[c];
    sc[c] = is * g;
    sh[c] = beta[c] - m * is * g;
}

// ---------------- segmented pooling (raw y; BN folded into MLP) ----------------
__global__ void k_pool(const f16* __restrict__ h, const int* __restrict__ grp,
                       float* __restrict__ pooled){
    int g = blockIdx.x;
    int c = blockIdx.y*256 + threadIdx.x;
    if (c >= EMB) return;
    int r0 = grp[g], r1 = grp[g+1];
    float s = 0.f;
    for (int r = r0; r < r1; r++) s += (float)h[(size_t)r*EMBP + c];
    pooled[g*EMB + c] = s;
}

__global__ __launch_bounds__(256) void k_mlp(const float* __restrict__ pooled, const int* __restrict__ grp,
                                             const float* __restrict__ sc, const float* __restrict__ sh,
                                             const float* __restrict__ W1, const float* __restrict__ b1,
                                             const float* __restrict__ W2, const float* __restrict__ b2,
                                             float* __restrict__ out){
    __shared__ float p[EMB];
    __shared__ float hid[128];
    int g = blockIdx.x, tid = threadIdx.x;
    int cnt = grp[g+1] - grp[g];
    float ic = 1.f / fmaxf((float)cnt, 1.f);
    for (int c = tid; c < EMB; c += 256){
        float v = pooled[g*EMB + c] * ic * sc[c] + sh[c];   // BN(mean) — affine commutes with mean
        p[c] = v > 0.f ? v : 0.f;
    }
    __syncthreads();
    if (tid < 128){
        float s = b1[tid];
        for (int k = 0; k < EMB; k++) s += p[k] * W1[k*128 + tid];
        hid[tid] = tanhf(s);
    }
    __syncthreads();
    if (tid < 64){
        float s = b2[tid];
        for (int k = 0; k < 128; k++) s += hid[k] * W2[k*64 + tid];
        out[g*64 + tid] = s;
    }
}

// ---------------- launch ----------------
extern "C" void kernel_launch(void* const* d_in, const int* in_sizes, int n_in,
                              void* d_out, int out_size, void* d_ws, size_t ws_size,
                              hipStream_t stream) {
    (void)in_sizes; (void)n_in; (void)out_size;
    const float* x    = (const float*)d_in[0];
    const int*   ei   = (const int*)  d_in[1];
    const int*   batch= (const int*)  d_in[2];
    const float* tW   = (const float*)d_in[3];
    const float* tb   = (const float*)d_in[4];
    const float* W0   = (const float*)d_in[5];
    const float* as0  = (const float*)d_in[6];
    const float* ad0  = (const float*)d_in[7];
    const float* b0   = (const float*)d_in[8];
    const float* g0   = (const float*)d_in[9];
    const float* be0  = (const float*)d_in[10];
    const float* W1   = (const float*)d_in[11];
    const float* as1  = (const float*)d_in[12];
    const float* ad1  = (const float*)d_in[13];
    const float* b1   = (const float*)d_in[14];
    const float* g1   = (const float*)d_in[15];
    const float* be1  = (const float*)d_in[16];
    const float* W2   = (const float*)d_in[17];
    const float* as2  = (const float*)d_in[18];
    const float* ad2  = (const float*)d_in[19];
    const float* b2   = (const float*)d_in[20];
    const float* g2   = (const float*)d_in[21];
    const float* be2  = (const float*)d_in[22];
    const float* mW1  = (const float*)d_in[23];
    const float* mb1  = (const float*)d_in[24];
    const float* mW2  = (const float*)d_in[25];
    const float* mb2  = (const float*)d_in[26];
    float* outp = (float*)d_out;

    size_t off = 0;
    auto carve = [&](size_t bytes) -> void* {
        void* p = (char*)d_ws + off;
        off = (off + bytes + 255) & ~(size_t)255;
        return p;
    };
    f16* big1 = (f16*)carve((size_t)NN*W3P*2);          // h / y buffers
    f16* big2 = (f16*)carve((size_t)NN*W3P*2);          // hp buffer
    f16* Wt   = (f16*)carve((size_t)W3*W3P*2);          // transposed (scaled) weights
    float* a_s   = (float*)carve((size_t)NN*3*4);
    float* a_d   = (float*)carve((size_t)NN*3*4);
    float* psum  = (float*)carve((size_t)64*W3*4);      // bnstat partials
    float* psq   = (float*)carve((size_t)64*W3*4);
    float* sc    = (float*)carve((size_t)W3*4);
    float* sh    = (float*)carve((size_t)W3*4);
    float* dvec  = (float*)carve((size_t)W3*4);
    float* pooled= (float*)carve((size_t)NGR*EMB*4);
    int*   grp   = (int*)carve((size_t)(NGR+1)*4);
    int*   deg   = (int*)carve((size_t)NN*4);           // reused as cursor
    int*   rp    = (int*)carve((size_t)(NN+1)*4);
    int*   csrc  = (int*)carve((size_t)ELP*4);

    if (ws_size < off) return;

    // CSR build
    k_zero_i32<<<cdiv_i(NN,256),256,0,stream>>>(deg, NN);
    k_deg<<<cdiv_i(ELP,256),256,0,stream>>>(ei, deg);
    k_scan<<<1,1024,0,stream>>>(deg, rp);
    k_copy_i32<<<cdiv_i(NN,256),256,0,stream>>>(rp, deg, NN);
    k_fill<<<cdiv_i(ELP,256),256,0,stream>>>(ei, deg, csrc);
    k_grp<<<1,256,0,stream>>>(batch, grp);

    // h0
    k_build_h<<<cdiv_i((long long)NN*EMBP,256),256,0,stream>>>(x, tW, tb, big1);

    struct Layer { const float* W; const float* as; const float* ad; const float* b;
                   const float* g; const float* be; int H; int K; int KP; };
    Layer layers[3] = {
        {W0, as0, ad0, b0, g0, be0, 3, EMB, EMBP},
        {W1, as1, ad1, b1, g1, be1, 3, W3,  W3P },
        {W2, as2, ad2, b2, g2, be2, 1, W3,  W3P },
    };

    for (int L = 0; L < 3; L++){
        Layer& ly = layers[L];
        int Wout  = ly.H * EMB;                 // 2340 / 2340 / 780
        int SPout = (Wout == W3) ? W3P : EMBP;  // 2368 / 2368 / 832
        const float* scale = (L == 0) ? nullptr : sc;

        // Wt <- W^T (scaled by prev BN scale); dvec <- sh @ W (L>0)
        dim3 tg(cdiv_i(Wout,32), cdiv_i(ly.KP,32));
        k_transpose<<<tg, dim3(32,8), 0, stream>>>(ly.W, Wt, scale, ly.K, Wout, ly.KP);
        k_zero_f32<<<cdiv_i(W3,256),256,0,stream>>>(dvec, W3);
        if (L > 0){
            dim3 dg(cdiv_i(Wout,256), DVEC_KSPLIT);
            k_dvec<<<dg,256,0,stream>>>(ly.W, sh, dvec, ly.K, Wout);
        }

        // hp = BN(h) @ W via f16 MFMA (BN folded), XCD-pinned strips, BK=64
        int Mtiles = cdiv_i(NN,128), NT = cdiv_i(Wout,128);
        int nb = ((Mtiles+7)/8)*8*NT;
        k_gemm_mfma<<<nb, 256, 0, stream>>>(big1, Wt, dvec, big2, NN, Wout, ly.KP, SPout, Mtiles, NT);

        // attention coefficients
        k_att<<<NN, ly.H*64, 0, stream>>>(big2, ly.as, ly.ad, a_s, a_d, ly.H, SPout);

        // softmax + aggregate + bias + tanh -> big1 (pre-BN y, pads zeroed)
        k_agg<<<NN,256,0,stream>>>(big2, rp, csrc, a_s, a_d, ly.b, big1, ly.H, SPout, Wout);

        // BN stats (partials, no atomics) + fold coefficients
        dim3 gs(cdiv_i(Wout/4,256), 64);
        k_bnstat<<<gs,256,0,stream>>>(big1, psum, psq, Wout, SPout);
        k_bnfin<<<cdiv_i(Wout,256),256,0,stream>>>(psum, psq, ly.g, ly.be, sc, sh, Wout);
    }

    // segmented pooling (raw y) + MLP (applies final BN affine on pooled means)
    dim3 pg(NGR, cdiv_i(EMB,256));
    k_pool<<<pg,256,0,stream>>>(big1, grp, pooled);
    k_mlp<<<NGR,256,0,stream>>>(pooled, grp, sc, sh, mW1, mb1, mW2, mb2, outp);
}